// Round 6
// baseline (213.934 us; speedup 1.0000x reference)
//
#include <hip/hip_runtime.h>
#include <hip/hip_bf16.h>
#include <stdint.h>

// Problem dims
#define T_TOK 2048
#define HD    1024
#define NE    8
#define FD    1408
#define F2D   2816

// GEMM tiling
#define BM 128
#define BK 32
#define MAXMT 40        // max M-tiles
#define MAXSLOTS 5120   // 40*128
#define FC1_NT 22       // FD/64
#define FC2_NT 16       // HD/64
#define FC1_NWG (FC1_NT * MAXMT)   // 880
#define FC2_NWG (FC2_NT * MAXMT)   // 640
#define FC1_CHUNK 110   // FC1_NWG/8
#define FC2_CHUNK 80    // FC2_NWG/8

typedef __attribute__((ext_vector_type(8))) short bf16x8;
typedef __attribute__((ext_vector_type(4))) float f32x4;

__device__ __forceinline__ unsigned short f2bf(float f) {
  unsigned int u = __float_as_uint(f);
  u += 0x7FFFu + ((u >> 16) & 1u);   // RNE
  return (unsigned short)(u >> 16);
}

#define GLL16(gp, lp) __builtin_amdgcn_global_load_lds( \
    (const __attribute__((address_space(1))) void*)(gp), \
    (__attribute__((address_space(3))) void*)(lp), 16, 0, 0)

// ---------------------------------------------------------------------------
// Router: one wave per token. f32 logits, softmax, top-2, counts; emits x bf16.
// ---------------------------------------------------------------------------
__global__ __launch_bounds__(256) void k_router(
    const float* __restrict__ x, const float* __restrict__ rw,
    unsigned short* __restrict__ xbf, int* __restrict__ ctrl,
    int* __restrict__ tok_e, float* __restrict__ tok_p)
{
  const int lane = threadIdx.x & 63;
  const int t = blockIdx.x * 4 + (threadIdx.x >> 6);
  const float* xr = x + (size_t)t * HD;

  float part[8];
#pragma unroll
  for (int e = 0; e < 8; ++e) part[e] = 0.f;

#pragma unroll
  for (int i = 0; i < 16; ++i) {
    const int h = i * 64 + lane;
    const float xv = xr[h];
    xbf[(size_t)t * HD + h] = f2bf(xv);
    const float4* rwr = reinterpret_cast<const float4*>(rw + (size_t)h * 8);
    float4 a = rwr[0], b = rwr[1];
    part[0] += xv * a.x; part[1] += xv * a.y; part[2] += xv * a.z; part[3] += xv * a.w;
    part[4] += xv * b.x; part[5] += xv * b.y; part[6] += xv * b.z; part[7] += xv * b.w;
  }
#pragma unroll
  for (int e = 0; e < 8; ++e) {
    float v = part[e];
#pragma unroll
    for (int d = 32; d; d >>= 1) v += __shfl_xor(v, d, 64);
    part[e] = v;
  }
  float m = part[0];
#pragma unroll
  for (int e = 1; e < 8; ++e) m = fmaxf(m, part[e]);
  float p[8], s = 0.f;
#pragma unroll
  for (int e = 0; e < 8; ++e) { p[e] = __expf(part[e] - m); s += p[e]; }
  const float inv = 1.f / s;
#pragma unroll
  for (int e = 0; e < 8; ++e) p[e] *= inv;

  int e0 = 0; float p0 = p[0];
#pragma unroll
  for (int e = 1; e < 8; ++e) if (p[e] > p0) { p0 = p[e]; e0 = e; }
  int e1 = -1; float p1 = -1.f;
#pragma unroll
  for (int e = 0; e < 8; ++e) if (e != e0 && p[e] > p1) { p1 = p[e]; e1 = e; }

  if (lane == 0) {
    tok_e[t * 2 + 0] = e0; tok_e[t * 2 + 1] = e1;
    tok_p[t * 2 + 0] = p0; tok_p[t * 2 + 1] = p1;
    atomicAdd(&ctrl[e0], 1);
    atomicAdd(&ctrl[e1], 1);
  }
}

// ---------------------------------------------------------------------------
// Offsets: BM-aligned scan; mtile tables; zero-pad slots; expert->XCD
// clustered wid->(mt,n) schedules.
// ctrl: [0..7]=cnt [8..15]=cursor [16..23]=off [24..63]=mtE [64..103]=mtB
// ---------------------------------------------------------------------------
__global__ __launch_bounds__(256) void k_offsets(
    int* __restrict__ ctrl, int* __restrict__ stok, float* __restrict__ sp,
    int* __restrict__ widmt1, int* __restrict__ widmt2)
{
  __shared__ int soff[8], scnt[8], sFirst[8], sNmt[8], sTake[8];
  __shared__ int sSpill;
  if (threadIdx.x == 0) {
    int o = 0, nm = 0, spill = 0;
    for (int e = 0; e < 8; ++e) {
      ctrl[16 + e] = o; soff[e] = o; scnt[e] = ctrl[e];
      const int n = ctrl[e];
      const int nmt = (n + BM - 1) / BM;
      sFirst[e] = nm; sNmt[e] = nmt; sTake[e] = nmt < 5 ? nmt : 5;
      if (nmt > 5) spill = 1;
      for (int j = 0; j < nmt; ++j) { ctrl[24 + nm] = e; ctrl[64 + nm] = o + j * BM; ++nm; }
      o += nmt * BM;
    }
    for (int i = nm; i < MAXMT; ++i) ctrl[24 + i] = -1;
    sSpill = spill;
  }
  __syncthreads();
  for (int i = threadIdx.x; i < FC1_NWG; i += 256) {
    const int e = i / FC1_CHUNK, r = i % FC1_CHUNK;
    const int j = r / FC1_NT, n = r % FC1_NT;
    widmt1[i] = (j < sTake[e]) ? (sFirst[e] + j) * 32 + n : -1;
  }
  for (int i = threadIdx.x; i < FC2_NWG; i += 256) {
    const int e = i / FC2_CHUNK, r = i % FC2_CHUNK;
    const int j = r / FC2_NT, n = r % FC2_NT;
    widmt2[i] = (j < sTake[e]) ? (sFirst[e] + j) * 32 + n : -1;
  }
  __syncthreads();
  if (sSpill && threadIdx.x == 0) {
    int cur = 0;
    for (int e = 0; e < 8; ++e)
      for (int j = 5; j < sNmt[e]; ++j)
        for (int n = 0; n < FC1_NT; ++n) {
          while (widmt1[cur] != -1) ++cur;
          widmt1[cur] = (sFirst[e] + j) * 32 + n;
        }
    cur = 0;
    for (int e = 0; e < 8; ++e)
      for (int j = 5; j < sNmt[e]; ++j)
        for (int n = 0; n < FC2_NT; ++n) {
          while (widmt2[cur] != -1) ++cur;
          widmt2[cur] = (sFirst[e] + j) * 32 + n;
        }
  }
  for (int e = 0; e < 8; ++e) {
    const int n = scnt[e], o = soff[e];
    const int padEnd = (n + BM - 1) / BM * BM;
    for (int j = n + (int)threadIdx.x; j < padEnd; j += 256) {
      stok[o + j] = 0; sp[o + j] = 0.f;
    }
  }
}

// ---------------------------------------------------------------------------
// Scatter tokens into per-expert compacted slot lists + inverse map tslot.
// ---------------------------------------------------------------------------
__global__ __launch_bounds__(256) void k_scatter(
    int* __restrict__ ctrl, const int* __restrict__ tok_e,
    const float* __restrict__ tok_p, int* __restrict__ stok,
    float* __restrict__ sp, int* __restrict__ tslot)
{
  const int t = blockIdx.x * 256 + threadIdx.x;
#pragma unroll
  for (int k = 0; k < 2; ++k) {
    const int e = tok_e[t * 2 + k];
    const float pp = tok_p[t * 2 + k];
    const int pos = atomicAdd(&ctrl[8 + e], 1);
    const int slot = ctrl[16 + e] + pos;
    stok[slot] = t; sp[slot] = pp;
    tslot[t * 2 + k] = slot;
  }
}

// ---------------------------------------------------------------------------
// fc1: y = X[slots] @ w1[e] (gate|up), fused silu(y1)*y2*p -> bf16 g.
// B-operand: f32 w1 read directly (coalesced columns), cvt+corner-turn in
// registers, conflict-free swizzled ds_write_b128 (write XOR == read XOR).
// A: global_load_lds from xbf. 3-buffer counted-vmcnt pipeline:
// per-wave issue order pinned [B(16), A(2)]; steady wait vmcnt(2) drains
// A(k=t) + B(k=t+1), leaves A(k=t+1).
// ---------------------------------------------------------------------------
__global__ __launch_bounds__(256) void k_fc1(
    const unsigned short* __restrict__ xbf,   // [T][H] bf16
    const float* __restrict__ w1,             // [E][H][2F] f32
    const int* __restrict__ ctrl,
    const int* __restrict__ stok,
    const float* __restrict__ sp,
    const int* __restrict__ widmt1,
    unsigned short* __restrict__ g)           // [MAXSLOTS][F] bf16
{
  const int bid = blockIdx.x;
  const int wid = (bid & 7) * FC1_CHUNK + (bid >> 3);
  const int packed = widmt1[wid];
  if (packed < 0) return;
  const int mt = packed >> 5;
  const int e = ctrl[24 + mt];
  const int rowbase = ctrl[64 + mt];
  const int n0 = (packed & 31) * 64;

  __shared__ unsigned short sA[3][BM * BK];   // 8 KB each
  __shared__ unsigned short sB1[3][64 * BK];  // 4 KB each
  __shared__ unsigned short sB2[3][64 * BK];  // total 48 KB

  const int tid = threadIdx.x;
  const int lane = tid & 63;
  const int wave = tid >> 6;
  const int wm = wave >> 1, wn = wave & 1;

  // A staging: linear LDS dest, pre-swizzled global source chunk (rule #21).
  const int schunk = (lane & 3) ^ ((lane >> 3) & 3);
  const unsigned short* aSrc[2];
#pragma unroll
  for (int t4 = 0; t4 < 2; ++t4) {
    const int row = (t4 * 4 + wave) * 16 + (lane >> 2);
    const int tok = stok[rowbase + row];
    aSrc[t4] = xbf + (size_t)tok * HD + schunk * 8;
  }

  // B staging: waves 0,1 -> gate (sB1); waves 2,3 -> up (sB2).
  // lane l = n-col; wave&1 = k-half (16 rows each). 16 coalesced f32 loads.
  const float* bbase = w1 + (size_t)e * HD * F2D
                     + ((wave & 2) ? (size_t)(FD + n0 + lane) : (size_t)(n0 + lane));
  float breg[16];
  auto BLOAD = [&](int k0) {
    const float* p = bbase + (size_t)(k0 + (wave & 1) * 16) * F2D;
#pragma unroll
    for (int j = 0; j < 16; ++j) breg[j] = p[(size_t)j * F2D];
  };
  auto BWRITE = [&](int buf) {
    unsigned short* dst = (wave & 2) ? sB2[buf] : sB1[buf];
    const int xr = (lane >> 1) & 3;
#pragma unroll
    for (int cc = 0; cc < 2; ++cc) {
      const int cw = (wave & 1) * 2 + cc;
      bf16x8 v;
#pragma unroll
      for (int jj = 0; jj < 8; ++jj) v[jj] = (short)f2bf(breg[cc * 8 + jj]);
      *(bf16x8*)&dst[lane * 32 + ((cw ^ xr) << 3)] = v;
    }
  };
  auto ASTAGE = [&](int buf, int k0) {
#pragma unroll
    for (int t4 = 0; t4 < 2; ++t4)
      GLL16(aSrc[t4] + k0, &sA[buf][(t4 * 4 + wave) * 512]);
  };

  // precomputed swizzled LDS read offsets
  const int c = lane >> 4;
  int aoff[4], boff[2];
#pragma unroll
  for (int m = 0; m < 4; ++m) {
    const int row = wm * 64 + m * 16 + (lane & 15);
    aoff[m] = row * 32 + ((c ^ ((row >> 1) & 3)) << 3);
  }
#pragma unroll
  for (int n = 0; n < 2; ++n) {
    const int row = wn * 32 + n * 16 + (lane & 15);
    boff[n] = row * 32 + ((c ^ ((row >> 1) & 3)) << 3);
  }

  const f32x4 zero = {0.f, 0.f, 0.f, 0.f};
  f32x4 acc1[4][2], acc2[4][2];
#pragma unroll
  for (int m = 0; m < 4; ++m)
#pragma unroll
    for (int n = 0; n < 2; ++n) { acc1[m][n] = zero; acc2[m][n] = zero; }

  const int NSTEP = HD / BK;   // 32
  // prologue: issue order pinned B-then-A so vmcnt counts are exact
  BLOAD(0);
  __builtin_amdgcn_sched_barrier(0);
  ASTAGE(0, 0);
  __builtin_amdgcn_sched_barrier(0);
  asm volatile("s_waitcnt vmcnt(2)" ::: "memory");  // B(k0) done, A(k0) in flight
  BWRITE(0);
  BLOAD(BK);
  __builtin_amdgcn_sched_barrier(0);
  ASTAGE(1, BK);
  __builtin_amdgcn_sched_barrier(0);
  asm volatile("s_waitcnt lgkmcnt(0)" ::: "memory");  // BWRITE(0) drained

  int bsel = 0;
  for (int t = 0; t < NSTEP; ++t) {
    if (t < NSTEP - 2) { asm volatile("s_waitcnt vmcnt(2)" ::: "memory"); }
    else               { asm volatile("s_waitcnt vmcnt(0)" ::: "memory"); }
    __builtin_amdgcn_s_barrier();
    __builtin_amdgcn_sched_barrier(0);
    int bnext = bsel + 1; if (bnext >= 3) bnext -= 3;
    int bn2 = bsel + 2; if (bn2 >= 3) bn2 -= 3;
    if (t + 1 < NSTEP) BWRITE(bnext);
    if (t + 2 < NSTEP) {
      BLOAD((t + 2) * BK);
      __builtin_amdgcn_sched_barrier(0);
      ASTAGE(bn2, (t + 2) * BK);
      __builtin_amdgcn_sched_barrier(0);
    }
    bf16x8 af[4], b1f[2], b2f[2];
#pragma unroll
    for (int m = 0; m < 4; ++m)
      af[m] = *(const bf16x8*)&sA[bsel][aoff[m]];
#pragma unroll
    for (int n = 0; n < 2; ++n) {
      b1f[n] = *(const bf16x8*)&sB1[bsel][boff[n]];
      b2f[n] = *(const bf16x8*)&sB2[bsel][boff[n]];
    }
    asm volatile("s_waitcnt lgkmcnt(0)" ::: "memory");
    __builtin_amdgcn_sched_barrier(0);
    __builtin_amdgcn_s_setprio(1);
#pragma unroll
    for (int m = 0; m < 4; ++m)
#pragma unroll
      for (int n = 0; n < 2; ++n) {
        acc1[m][n] = __builtin_amdgcn_mfma_f32_16x16x32_bf16(af[m], b1f[n], acc1[m][n], 0, 0, 0);
        acc2[m][n] = __builtin_amdgcn_mfma_f32_16x16x32_bf16(af[m], b2f[n], acc2[m][n], 0, 0, 0);
      }
    __builtin_amdgcn_s_setprio(0);
    bsel = bnext;
  }

  float prv[4][4];
#pragma unroll
  for (int m = 0; m < 4; ++m)
#pragma unroll
    for (int r = 0; r < 4; ++r)
      prv[m][r] = sp[rowbase + wm * 64 + m * 16 + (lane >> 4) * 4 + r];

#pragma unroll
  for (int m = 0; m < 4; ++m) {
    const int rb = rowbase + wm * 64 + m * 16 + (lane >> 4) * 4;
#pragma unroll
    for (int n = 0; n < 2; ++n) {
      const int col = n0 + wn * 32 + n * 16 + (lane & 15);
#pragma unroll
      for (int r = 0; r < 4; ++r) {
        const float y1 = acc1[m][n][r];
        const float y2 = acc2[m][n][r];
        const float gv = y1 / (1.f + __expf(-y1)) * y2 * prv[m][r];
        g[(size_t)(rb + r) * FD + col] = f2bf(gv);
      }
    }
  }
}

// ---------------------------------------------------------------------------
// fc2: o[slot] = g[slot] @ w2[e], plain f32 stores. Same fused-B pattern:
// each wave loads 8 f32 k-rows of its column, one swizzled ds_write_b128.
// ---------------------------------------------------------------------------
__global__ __launch_bounds__(256) void k_fc2(
    const unsigned short* __restrict__ g,     // [MAXSLOTS][F] bf16
    const float* __restrict__ w2,             // [E][F][H] f32
    const int* __restrict__ ctrl,
    const int* __restrict__ widmt2,
    float* __restrict__ o)                    // [MAXSLOTS][H] f32
{
  const int bid = blockIdx.x;
  const int wid = (bid & 7) * FC2_CHUNK + (bid >> 3);
  const int packed = widmt2[wid];
  if (packed < 0) return;
  const int mt = packed >> 5;
  const int e = ctrl[24 + mt];
  const int rowbase = ctrl[64 + mt];
  const int n0 = (packed & 31) * 64;

  __shared__ unsigned short sA[3][BM * BK];   // 8 KB each
  __shared__ unsigned short sB[3][64 * BK];   // 4 KB each; total 36 KB

  const int tid = threadIdx.x;
  const int lane = tid & 63;
  const int wave = tid >> 6;
  const int wm = wave >> 1, wn = wave & 1;

  const int schunk = (lane & 3) ^ ((lane >> 3) & 3);
  const unsigned short* aSrc[2];
#pragma unroll
  for (int t4 = 0; t4 < 2; ++t4) {
    const int row = (t4 * 4 + wave) * 16 + (lane >> 2);
    aSrc[t4] = g + (size_t)(rowbase + row) * FD + schunk * 8;
  }

  // B: lane = n-col (h-dim), wave = k-chunk (8 f-rows each)
  const float* bbase = w2 + (size_t)e * FD * HD + n0 + lane;
  float breg[8];
  auto BLOAD = [&](int k0) {
    const float* p = bbase + (size_t)(k0 + wave * 8) * HD;
#pragma unroll
    for (int j = 0; j < 8; ++j) breg[j] = p[(size_t)j * HD];
  };
  auto BWRITE = [&](int buf) {
    const int xr = (lane >> 1) & 3;
    bf16x8 v;
#pragma unroll
    for (int jj = 0; jj < 8; ++jj) v[jj] = (short)f2bf(breg[jj]);
    *(bf16x8*)&sB[buf][lane * 32 + ((wave ^ xr) << 3)] = v;
  };
  auto ASTAGE = [&](int buf, int k0) {
#pragma unroll
    for (int t4 = 0; t4 < 2; ++t4)
      GLL16(aSrc[t4] + k0, &sA[buf][(t4 * 4 + wave) * 512]);
  };

  const int c = lane >> 4;
  int aoff[4], boff[2];
#pragma unroll
  for (int m = 0; m < 4; ++m) {
    const int row = wm * 64 + m * 16 + (lane & 15);
    aoff[m] = row * 32 + ((c ^ ((row >> 1) & 3)) << 3);
  }
#pragma unroll
  for (int n = 0; n < 2; ++n) {
    const int row = wn * 32 + n * 16 + (lane & 15);
    boff[n] = row * 32 + ((c ^ ((row >> 1) & 3)) << 3);
  }

  const f32x4 zero = {0.f, 0.f, 0.f, 0.f};
  f32x4 acc[4][2];
#pragma unroll
  for (int m = 0; m < 4; ++m)
#pragma unroll
    for (int n = 0; n < 2; ++n) acc[m][n] = zero;

  const int NSTEP = FD / BK;   // 44
  BLOAD(0);
  __builtin_amdgcn_sched_barrier(0);
  ASTAGE(0, 0);
  __builtin_amdgcn_sched_barrier(0);
  asm volatile("s_waitcnt vmcnt(2)" ::: "memory");
  BWRITE(0);
  BLOAD(BK);
  __builtin_amdgcn_sched_barrier(0);
  ASTAGE(1, BK);
  __builtin_amdgcn_sched_barrier(0);
  asm volatile("s_waitcnt lgkmcnt(0)" ::: "memory");

  int bsel = 0;
  for (int t = 0; t < NSTEP; ++t) {
    if (t < NSTEP - 2) { asm volatile("s_waitcnt vmcnt(2)" ::: "memory"); }
    else               { asm volatile("s_waitcnt vmcnt(0)" ::: "memory"); }
    __builtin_amdgcn_s_barrier();
    __builtin_amdgcn_sched_barrier(0);
    int bnext = bsel + 1; if (bnext >= 3) bnext -= 3;
    int bn2 = bsel + 2; if (bn2 >= 3) bn2 -= 3;
    if (t + 1 < NSTEP) BWRITE(bnext);
    if (t + 2 < NSTEP) {
      BLOAD((t + 2) * BK);
      __builtin_amdgcn_sched_barrier(0);
      ASTAGE(bn2, (t + 2) * BK);
      __builtin_amdgcn_sched_barrier(0);
    }
    bf16x8 af[4], bf[2];
#pragma unroll
    for (int m = 0; m < 4; ++m)
      af[m] = *(const bf16x8*)&sA[bsel][aoff[m]];
#pragma unroll
    for (int n = 0; n < 2; ++n)
      bf[n] = *(const bf16x8*)&sB[bsel][boff[n]];
    asm volatile("s_waitcnt lgkmcnt(0)" ::: "memory");
    __builtin_amdgcn_sched_barrier(0);
    __builtin_amdgcn_s_setprio(1);
#pragma unroll
    for (int m = 0; m < 4; ++m)
#pragma unroll
      for (int n = 0; n < 2; ++n)
        acc[m][n] = __builtin_amdgcn_mfma_f32_16x16x32_bf16(af[m], bf[n], acc[m][n], 0, 0, 0);
    __builtin_amdgcn_s_setprio(0);
    bsel = bnext;
  }

#pragma unroll
  for (int m = 0; m < 4; ++m) {
    const int rb = rowbase + wm * 64 + m * 16 + (lane >> 4) * 4;
#pragma unroll
    for (int n = 0; n < 2; ++n) {
      const int col = n0 + wn * 32 + n * 16 + (lane & 15);
#pragma unroll
      for (int r = 0; r < 4; ++r)
        o[(size_t)(rb + r) * HD + col] = acc[m][n][r];
    }
  }
}

// ---------------------------------------------------------------------------
// Combine: out[t] = o[slotA(t)] + o[slotB(t)]  (prob folded into g in fc1).
// ---------------------------------------------------------------------------
__global__ __launch_bounds__(256) void k_combine(
    const float* __restrict__ o, const int* __restrict__ tslot,
    float* __restrict__ out)
{
  const int t = blockIdx.x;
  const int c4 = threadIdx.x;
  const int sA = tslot[t * 2], sB = tslot[t * 2 + 1];
  const float4 a = reinterpret_cast<const float4*>(o)[(size_t)sA * 256 + c4];
  const float4 b = reinterpret_cast<const float4*>(o)[(size_t)sB * 256 + c4];
  float4 r;
  r.x = a.x + b.x; r.y = a.y + b.y; r.z = a.z + b.z; r.w = a.w + b.w;
  reinterpret_cast<float4*>(out)[(size_t)t * 256 + c4] = r;
}

// ---------------------------------------------------------------------------
extern "C" void kernel_launch(void* const* d_in, const int* in_sizes, int n_in,
                              void* d_out, int out_size, void* d_ws, size_t ws_size,
                              hipStream_t stream)
{
  const float* x  = (const float*)d_in[0];   // [2048,1,1024]
  const float* rw = (const float*)d_in[1];   // [1024,8]
  const float* w1 = (const float*)d_in[2];   // [8,1024,2816]
  const float* w2 = (const float*)d_in[3];   // [8,1408,1024]
  float* out = (float*)d_out;
  char* ws = (char*)d_ws;

  // ws layout (bytes)
  int*   ctrl   = (int*)(ws + 0);                   // 1 KB
  int*   tok_e  = (int*)(ws + 1024);                // 16 KB
  float* tok_p  = (float*)(ws + 17408);             // 16 KB
  int*   stok   = (int*)(ws + 33792);               // 20 KB
  float* sp     = (float*)(ws + 54272);             // 20 KB
  int*   tslot  = (int*)(ws + 74752);               // 16 KB
  int*   widmt1 = (int*)(ws + 91136);               // 3.5 KB
  int*   widmt2 = (int*)(ws + 94656);               // 2.5 KB
  unsigned short* xbf = (unsigned short*)(ws + 97280);   // [T][H]     4 MB
  unsigned short* g   = (unsigned short*)(ws + 4291584); // [SLOTS][F] 14.5 MB
  float*          o   = (float*)(ws + 18709504);         // [SLOTS][H] 21 MB

  hipMemsetAsync(ws, 0, 1024, stream);

  k_router<<<T_TOK / 4, 256, 0, stream>>>(x, rw, xbf, ctrl, tok_e, tok_p);
  k_offsets<<<1, 256, 0, stream>>>(ctrl, stok, sp, widmt1, widmt2);
  k_scatter<<<T_TOK / 256, 256, 0, stream>>>(ctrl, tok_e, tok_p, stok, sp, tslot);
  k_fc1<<<FC1_NWG, 256, 0, stream>>>(xbf, w1, ctrl, stok, sp, widmt1, g);
  k_fc2<<<FC2_NWG, 256, 0, stream>>>(g, w2, ctrl, widmt2, o);
  k_combine<<<T_TOK, 256, 0, stream>>>(o, tslot, out);
}

// Round 7
// 202.102 us; speedup vs baseline: 1.0585x; 1.0585x over previous
//
#include <hip/hip_runtime.h>
#include <hip/hip_bf16.h>
#include <stdint.h>

// Problem dims
#define T_TOK 2048
#define HD    1024
#define NE    8
#define FD    1408
#define F2D   2816

// GEMM tiling
#define BM 128
#define BK 32
#define MAXMT 40        // max M-tiles
#define MAXSLOTS 5120   // 40*128
#define FC1_NT 22       // FD/64
#define FC2_NT 16       // HD/64
#define FC1_NWG (FC1_NT * MAXMT)   // 880
#define FC2_NWG (FC2_NT * MAXMT)   // 640
#define FC1_CHUNK 110   // FC1_NWG/8
#define FC2_CHUNK 80    // FC2_NWG/8

// merged prep kernel partition
#define PREP_TR1 5632   // (F2D/64)*(HD/64)*NE = 44*16*8
#define PREP_TR2 2816   // (HD/64)*(FD/64)*NE = 16*22*8
#define PREP_ROUTER 512 // T_TOK/4
#define PREP_NWG (PREP_TR1 + PREP_TR2 + PREP_ROUTER)

typedef __attribute__((ext_vector_type(8))) short bf16x8;
typedef __attribute__((ext_vector_type(4))) float f32x4;

__device__ __forceinline__ unsigned short f2bf(float f) {
  unsigned int u = __float_as_uint(f);
  u += 0x7FFFu + ((u >> 16) & 1u);   // RNE
  return (unsigned short)(u >> 16);
}

#define GLL16(gp, lp) __builtin_amdgcn_global_load_lds( \
    (const __attribute__((address_space(1))) void*)(gp), \
    (__attribute__((address_space(3))) void*)(lp), 16, 0, 0)

// ---------------------------------------------------------------------------
// Prep (merged): blocks [0,PREP_TR1) transpose+cvt w1; [PREP_TR1,+PREP_TR2)
// transpose+cvt w2; last PREP_ROUTER blocks run the router (4 tokens each).
// All three are independent; merging removes 2 dispatch gaps and hides the
// router's 8 MB under the transpose's BW-bound phase.
// ---------------------------------------------------------------------------
__global__ __launch_bounds__(256) void k_prep(
    const float* __restrict__ x,  const float* __restrict__ rw,
    const float* __restrict__ w1, const float* __restrict__ w2,
    unsigned short* __restrict__ w1t, unsigned short* __restrict__ w2t,
    unsigned short* __restrict__ xbf, int* __restrict__ ctrl,
    int* __restrict__ tok_e, float* __restrict__ tok_p)
{
  const int b = blockIdx.x;
  if (b < PREP_TR1 + PREP_TR2) {
    // ---- transpose + cvt: src [z][R][C] f32 -> dst [z][C][R] bf16 ----
    const float* src; unsigned short* dst; int R, C, r0, c0;
    if (b < PREP_TR1) {
      const int z = b / (44 * 16), rem = b % (44 * 16);
      R = HD; C = F2D;
      c0 = (rem % 44) * 64; r0 = (rem / 44) * 64;
      src = w1 + (size_t)z * R * C; dst = w1t + (size_t)z * R * C;
    } else {
      const int bb = b - PREP_TR1;
      const int z = bb / (16 * 22), rem = bb % (16 * 22);
      R = FD; C = HD;
      c0 = (rem % 16) * 64; r0 = (rem / 16) * 64;
      src = w2 + (size_t)z * R * C; dst = w2t + (size_t)z * R * C;
    }
    __shared__ float tile[64][65];
    const int tr = threadIdx.x >> 4;
    const int tc = (threadIdx.x & 15) * 4;
#pragma unroll
    for (int p = 0; p < 4; ++p) {
      const int r = p * 16 + tr;
      float4 v = *reinterpret_cast<const float4*>(&src[(size_t)(r0 + r) * C + c0 + tc]);
      tile[r][tc + 0] = v.x; tile[r][tc + 1] = v.y;
      tile[r][tc + 2] = v.z; tile[r][tc + 3] = v.w;
    }
    __syncthreads();
#pragma unroll
    for (int p = 0; p < 4; ++p) {
      const int c = p * 16 + tr;
      ushort4 o;
      o.x = f2bf(tile[tc + 0][c]);
      o.y = f2bf(tile[tc + 1][c]);
      o.z = f2bf(tile[tc + 2][c]);
      o.w = f2bf(tile[tc + 3][c]);
      *reinterpret_cast<ushort4*>(&dst[(size_t)(c0 + c) * R + r0 + tc]) = o;
    }
    return;
  }

  // ---- router: one wave per token ----
  const int lane = threadIdx.x & 63;
  const int t = (b - PREP_TR1 - PREP_TR2) * 4 + (threadIdx.x >> 6);
  const float* xr = x + (size_t)t * HD;

  float part[8];
#pragma unroll
  for (int e = 0; e < 8; ++e) part[e] = 0.f;

#pragma unroll
  for (int i = 0; i < 16; ++i) {
    const int h = i * 64 + lane;
    const float xv = xr[h];
    xbf[(size_t)t * HD + h] = f2bf(xv);
    const float4* rwr = reinterpret_cast<const float4*>(rw + (size_t)h * 8);
    float4 a = rwr[0], bb = rwr[1];
    part[0] += xv * a.x; part[1] += xv * a.y; part[2] += xv * a.z; part[3] += xv * a.w;
    part[4] += xv * bb.x; part[5] += xv * bb.y; part[6] += xv * bb.z; part[7] += xv * bb.w;
  }
#pragma unroll
  for (int e = 0; e < 8; ++e) {
    float v = part[e];
#pragma unroll
    for (int d = 32; d; d >>= 1) v += __shfl_xor(v, d, 64);
    part[e] = v;
  }
  float m = part[0];
#pragma unroll
  for (int e = 1; e < 8; ++e) m = fmaxf(m, part[e]);
  float p[8], s = 0.f;
#pragma unroll
  for (int e = 0; e < 8; ++e) { p[e] = __expf(part[e] - m); s += p[e]; }
  const float inv = 1.f / s;
#pragma unroll
  for (int e = 0; e < 8; ++e) p[e] *= inv;

  int e0 = 0; float p0 = p[0];
#pragma unroll
  for (int e = 1; e < 8; ++e) if (p[e] > p0) { p0 = p[e]; e0 = e; }
  int e1 = -1; float p1 = -1.f;
#pragma unroll
  for (int e = 0; e < 8; ++e) if (e != e0 && p[e] > p1) { p1 = p[e]; e1 = e; }

  if (lane == 0) {
    tok_e[t * 2 + 0] = e0; tok_e[t * 2 + 1] = e1;
    tok_p[t * 2 + 0] = p0; tok_p[t * 2 + 1] = p1;
    atomicAdd(&ctrl[e0], 1);
    atomicAdd(&ctrl[e1], 1);
  }
}

// ---------------------------------------------------------------------------
// Offsets: BM-aligned scan; mtile tables; zero-pad slots; expert->XCD
// clustered wid->(mt,n) schedules.
// ctrl: [0..7]=cnt [8..15]=cursor [16..23]=off [24..63]=mtE [64..103]=mtB
// ---------------------------------------------------------------------------
__global__ __launch_bounds__(256) void k_offsets(
    int* __restrict__ ctrl, int* __restrict__ stok, float* __restrict__ sp,
    int* __restrict__ widmt1, int* __restrict__ widmt2)
{
  __shared__ int soff[8], scnt[8], sFirst[8], sNmt[8], sTake[8];
  __shared__ int sSpill;
  if (threadIdx.x == 0) {
    int o = 0, nm = 0, spill = 0;
    for (int e = 0; e < 8; ++e) {
      ctrl[16 + e] = o; soff[e] = o; scnt[e] = ctrl[e];
      const int n = ctrl[e];
      const int nmt = (n + BM - 1) / BM;
      sFirst[e] = nm; sNmt[e] = nmt; sTake[e] = nmt < 5 ? nmt : 5;
      if (nmt > 5) spill = 1;
      for (int j = 0; j < nmt; ++j) { ctrl[24 + nm] = e; ctrl[64 + nm] = o + j * BM; ++nm; }
      o += nmt * BM;
    }
    for (int i = nm; i < MAXMT; ++i) ctrl[24 + i] = -1;
    sSpill = spill;
  }
  __syncthreads();
  for (int i = threadIdx.x; i < FC1_NWG; i += 256) {
    const int e = i / FC1_CHUNK, r = i % FC1_CHUNK;
    const int j = r / FC1_NT, n = r % FC1_NT;
    widmt1[i] = (j < sTake[e]) ? (sFirst[e] + j) * 32 + n : -1;
  }
  for (int i = threadIdx.x; i < FC2_NWG; i += 256) {
    const int e = i / FC2_CHUNK, r = i % FC2_CHUNK;
    const int j = r / FC2_NT, n = r % FC2_NT;
    widmt2[i] = (j < sTake[e]) ? (sFirst[e] + j) * 32 + n : -1;
  }
  __syncthreads();
  if (sSpill && threadIdx.x == 0) {
    int cur = 0;
    for (int e = 0; e < 8; ++e)
      for (int j = 5; j < sNmt[e]; ++j)
        for (int n = 0; n < FC1_NT; ++n) {
          while (widmt1[cur] != -1) ++cur;
          widmt1[cur] = (sFirst[e] + j) * 32 + n;
        }
    cur = 0;
    for (int e = 0; e < 8; ++e)
      for (int j = 5; j < sNmt[e]; ++j)
        for (int n = 0; n < FC2_NT; ++n) {
          while (widmt2[cur] != -1) ++cur;
          widmt2[cur] = (sFirst[e] + j) * 32 + n;
        }
  }
  for (int e = 0; e < 8; ++e) {
    const int n = scnt[e], o = soff[e];
    const int padEnd = (n + BM - 1) / BM * BM;
    for (int j = n + (int)threadIdx.x; j < padEnd; j += 256) {
      stok[o + j] = 0; sp[o + j] = 0.f;
    }
  }
}

// ---------------------------------------------------------------------------
// Scatter tokens into per-expert compacted slot lists + inverse map tslot.
// ---------------------------------------------------------------------------
__global__ __launch_bounds__(256) void k_scatter(
    int* __restrict__ ctrl, const int* __restrict__ tok_e,
    const float* __restrict__ tok_p, int* __restrict__ stok,
    float* __restrict__ sp, int* __restrict__ tslot)
{
  const int t = blockIdx.x * 256 + threadIdx.x;
#pragma unroll
  for (int k = 0; k < 2; ++k) {
    const int e = tok_e[t * 2 + k];
    const float pp = tok_p[t * 2 + k];
    const int pos = atomicAdd(&ctrl[8 + e], 1);
    const int slot = ctrl[16 + e] + pos;
    stok[slot] = t; sp[slot] = pp;
    tslot[t * 2 + k] = slot;
  }
}

// ---------------------------------------------------------------------------
// fc1: y = X[slots] @ w1[e] (gate|up), fused silu(y1)*y2*p -> bf16 g.
// 3-buffer depth-2 counted-vmcnt pipeline, swizzled conflict-free LDS,
// expert->XCD clustered schedule. (round-5 verified version)
// ---------------------------------------------------------------------------
__global__ __launch_bounds__(256) void k_fc1(
    const unsigned short* __restrict__ xbf,   // [T][H] bf16
    const unsigned short* __restrict__ w1t,   // [E][2F][H] bf16
    const int* __restrict__ ctrl,
    const int* __restrict__ stok,
    const float* __restrict__ sp,
    const int* __restrict__ widmt1,
    unsigned short* __restrict__ g)           // [MAXSLOTS][F] bf16
{
  const int bid = blockIdx.x;
  const int wid = (bid & 7) * FC1_CHUNK + (bid >> 3);
  const int packed = widmt1[wid];
  if (packed < 0) return;
  const int mt = packed >> 5;
  const int e = ctrl[24 + mt];
  const int rowbase = ctrl[64 + mt];
  const int n0 = (packed & 31) * 64;

  __shared__ unsigned short sA[3][BM * BK];   // 8 KB each
  __shared__ unsigned short sB1[3][64 * BK];  // 4 KB each
  __shared__ unsigned short sB2[3][64 * BK];  // total 48 KB

  const int tid = threadIdx.x;
  const int lane = tid & 63;
  const int wave = tid >> 6;
  const int wm = wave >> 1, wn = wave & 1;

  const int schunk = (lane & 3) ^ ((lane >> 3) & 3);
  const unsigned short* aSrc[2];
#pragma unroll
  for (int t4 = 0; t4 < 2; ++t4) {
    const int row = (t4 * 4 + wave) * 16 + (lane >> 2);
    const int tok = stok[rowbase + row];
    aSrc[t4] = xbf + (size_t)tok * HD + schunk * 8;
  }
  const int brow = wave * 16 + (lane >> 2);
  const unsigned short* b1Src = w1t + ((size_t)e * F2D + n0 + brow) * HD + schunk * 8;
  const unsigned short* b2Src = w1t + ((size_t)e * F2D + FD + n0 + brow) * HD + schunk * 8;

  const int c = lane >> 4;
  int aoff[4], boff[2];
#pragma unroll
  for (int m = 0; m < 4; ++m) {
    const int row = wm * 64 + m * 16 + (lane & 15);
    aoff[m] = row * 32 + ((c ^ ((row >> 1) & 3)) << 3);
  }
#pragma unroll
  for (int n = 0; n < 2; ++n) {
    const int row = wn * 32 + n * 16 + (lane & 15);
    boff[n] = row * 32 + ((c ^ ((row >> 1) & 3)) << 3);
  }

  const f32x4 zero = {0.f, 0.f, 0.f, 0.f};
  f32x4 acc1[4][2], acc2[4][2];
#pragma unroll
  for (int m = 0; m < 4; ++m)
#pragma unroll
    for (int n = 0; n < 2; ++n) { acc1[m][n] = zero; acc2[m][n] = zero; }

  auto STAGE = [&](int buf, int k0) {
#pragma unroll
    for (int t4 = 0; t4 < 2; ++t4)
      GLL16(aSrc[t4] + k0, &sA[buf][(t4 * 4 + wave) * 512]);
    GLL16(b1Src + k0, &sB1[buf][wave * 512]);
    GLL16(b2Src + k0, &sB2[buf][wave * 512]);
  };

  const int NSTEP = HD / BK;   // 32
  STAGE(0, 0);
  STAGE(1, BK);
  int bsel = 0;
  for (int t = 0; t < NSTEP; ++t) {
    if (t < NSTEP - 2) { asm volatile("s_waitcnt vmcnt(4)" ::: "memory"); }
    else               { asm volatile("s_waitcnt vmcnt(0)" ::: "memory"); }
    __builtin_amdgcn_s_barrier();
    __builtin_amdgcn_sched_barrier(0);
    if (t + 2 < NSTEP) {
      int bnext = bsel + 2; if (bnext >= 3) bnext -= 3;
      STAGE(bnext, (t + 2) * BK);
    }
    bf16x8 af[4], b1f[2], b2f[2];
#pragma unroll
    for (int m = 0; m < 4; ++m)
      af[m] = *(const bf16x8*)&sA[bsel][aoff[m]];
#pragma unroll
    for (int n = 0; n < 2; ++n) {
      b1f[n] = *(const bf16x8*)&sB1[bsel][boff[n]];
      b2f[n] = *(const bf16x8*)&sB2[bsel][boff[n]];
    }
    asm volatile("s_waitcnt lgkmcnt(0)" ::: "memory");
    __builtin_amdgcn_sched_barrier(0);
    __builtin_amdgcn_s_setprio(1);
#pragma unroll
    for (int m = 0; m < 4; ++m)
#pragma unroll
      for (int n = 0; n < 2; ++n) {
        acc1[m][n] = __builtin_amdgcn_mfma_f32_16x16x32_bf16(af[m], b1f[n], acc1[m][n], 0, 0, 0);
        acc2[m][n] = __builtin_amdgcn_mfma_f32_16x16x32_bf16(af[m], b2f[n], acc2[m][n], 0, 0, 0);
      }
    __builtin_amdgcn_s_setprio(0);
    bsel = bsel + 1 == 3 ? 0 : bsel + 1;
  }

  float prv[4][4];
#pragma unroll
  for (int m = 0; m < 4; ++m)
#pragma unroll
    for (int r = 0; r < 4; ++r)
      prv[m][r] = sp[rowbase + wm * 64 + m * 16 + (lane >> 4) * 4 + r];

#pragma unroll
  for (int m = 0; m < 4; ++m) {
    const int rb = rowbase + wm * 64 + m * 16 + (lane >> 4) * 4;
#pragma unroll
    for (int n = 0; n < 2; ++n) {
      const int col = n0 + wn * 32 + n * 16 + (lane & 15);
#pragma unroll
      for (int r = 0; r < 4; ++r) {
        const float y1 = acc1[m][n][r];
        const float y2 = acc2[m][n][r];
        const float gv = y1 / (1.f + __expf(-y1)) * y2 * prv[m][r];
        g[(size_t)(rb + r) * FD + col] = f2bf(gv);
      }
    }
  }
}

// ---------------------------------------------------------------------------
// fc2: o[slot] = g[slot] @ w2[e], plain f32 stores, 3-buffer counted-vmcnt
// pipeline. (round-5 verified version)
// ---------------------------------------------------------------------------
__global__ __launch_bounds__(256) void k_fc2(
    const unsigned short* __restrict__ g,     // [MAXSLOTS][F] bf16
    const unsigned short* __restrict__ w2t,   // [E][H][F] bf16
    const int* __restrict__ ctrl,
    const int* __restrict__ widmt2,
    float* __restrict__ o)                    // [MAXSLOTS][H] f32
{
  const int bid = blockIdx.x;
  const int wid = (bid & 7) * FC2_CHUNK + (bid >> 3);
  const int packed = widmt2[wid];
  if (packed < 0) return;
  const int mt = packed >> 5;
  const int e = ctrl[24 + mt];
  const int rowbase = ctrl[64 + mt];
  const int n0 = (packed & 31) * 64;

  __shared__ unsigned short sA[3][BM * BK];   // 8 KB each
  __shared__ unsigned short sB[3][64 * BK];   // 4 KB each; total 36 KB

  const int tid = threadIdx.x;
  const int lane = tid & 63;
  const int wave = tid >> 6;
  const int wm = wave >> 1, wn = wave & 1;

  const int schunk = (lane & 3) ^ ((lane >> 3) & 3);
  const unsigned short* aSrc[2];
#pragma unroll
  for (int t4 = 0; t4 < 2; ++t4) {
    const int row = (t4 * 4 + wave) * 16 + (lane >> 2);
    aSrc[t4] = g + (size_t)(rowbase + row) * FD + schunk * 8;
  }
  const int brow = wave * 16 + (lane >> 2);
  const unsigned short* bSrc = w2t + ((size_t)e * HD + n0 + brow) * FD + schunk * 8;

  const int c = lane >> 4;
  int aoff[4], boff[2];
#pragma unroll
  for (int m = 0; m < 4; ++m) {
    const int row = wm * 64 + m * 16 + (lane & 15);
    aoff[m] = row * 32 + ((c ^ ((row >> 1) & 3)) << 3);
  }
#pragma unroll
  for (int n = 0; n < 2; ++n) {
    const int row = wn * 32 + n * 16 + (lane & 15);
    boff[n] = row * 32 + ((c ^ ((row >> 1) & 3)) << 3);
  }

  const f32x4 zero = {0.f, 0.f, 0.f, 0.f};
  f32x4 acc[4][2];
#pragma unroll
  for (int m = 0; m < 4; ++m)
#pragma unroll
    for (int n = 0; n < 2; ++n) acc[m][n] = zero;

  auto STAGE = [&](int buf, int k0) {
#pragma unroll
    for (int t4 = 0; t4 < 2; ++t4)
      GLL16(aSrc[t4] + k0, &sA[buf][(t4 * 4 + wave) * 512]);
    GLL16(bSrc + k0, &sB[buf][wave * 512]);
  };

  const int NSTEP = FD / BK;   // 44
  STAGE(0, 0);
  STAGE(1, BK);
  int bsel = 0;
  for (int t = 0; t < NSTEP; ++t) {
    if (t < NSTEP - 2) { asm volatile("s_waitcnt vmcnt(3)" ::: "memory"); }
    else               { asm volatile("s_waitcnt vmcnt(0)" ::: "memory"); }
    __builtin_amdgcn_s_barrier();
    __builtin_amdgcn_sched_barrier(0);
    if (t + 2 < NSTEP) {
      int bnext = bsel + 2; if (bnext >= 3) bnext -= 3;
      STAGE(bnext, (t + 2) * BK);
    }
    bf16x8 af[4], bf[2];
#pragma unroll
    for (int m = 0; m < 4; ++m)
      af[m] = *(const bf16x8*)&sA[bsel][aoff[m]];
#pragma unroll
    for (int n = 0; n < 2; ++n)
      bf[n] = *(const bf16x8*)&sB[bsel][boff[n]];
    asm volatile("s_waitcnt lgkmcnt(0)" ::: "memory");
    __builtin_amdgcn_sched_barrier(0);
    __builtin_amdgcn_s_setprio(1);
#pragma unroll
    for (int m = 0; m < 4; ++m)
#pragma unroll
      for (int n = 0; n < 2; ++n)
        acc[m][n] = __builtin_amdgcn_mfma_f32_16x16x32_bf16(af[m], bf[n], acc[m][n], 0, 0, 0);
    __builtin_amdgcn_s_setprio(0);
    bsel = bsel + 1 == 3 ? 0 : bsel + 1;
  }

#pragma unroll
  for (int m = 0; m < 4; ++m) {
    const int rb = rowbase + wm * 64 + m * 16 + (lane >> 4) * 4;
#pragma unroll
    for (int n = 0; n < 2; ++n) {
      const int col = n0 + wn * 32 + n * 16 + (lane & 15);
#pragma unroll
      for (int r = 0; r < 4; ++r)
        o[(size_t)(rb + r) * HD + col] = acc[m][n][r];
    }
  }
}

// ---------------------------------------------------------------------------
// Combine: out[t] = o[slotA(t)] + o[slotB(t)]  (prob folded into g in fc1).
// ---------------------------------------------------------------------------
__global__ __launch_bounds__(256) void k_combine(
    const float* __restrict__ o, const int* __restrict__ tslot,
    float* __restrict__ out)
{
  const int t = blockIdx.x;
  const int c4 = threadIdx.x;
  const int sA = tslot[t * 2], sB = tslot[t * 2 + 1];
  const float4 a = reinterpret_cast<const float4*>(o)[(size_t)sA * 256 + c4];
  const float4 b = reinterpret_cast<const float4*>(o)[(size_t)sB * 256 + c4];
  float4 r;
  r.x = a.x + b.x; r.y = a.y + b.y; r.z = a.z + b.z; r.w = a.w + b.w;
  reinterpret_cast<float4*>(out)[(size_t)t * 256 + c4] = r;
}

// ---------------------------------------------------------------------------
extern "C" void kernel_launch(void* const* d_in, const int* in_sizes, int n_in,
                              void* d_out, int out_size, void* d_ws, size_t ws_size,
                              hipStream_t stream)
{
  const float* x  = (const float*)d_in[0];   // [2048,1,1024]
  const float* rw = (const float*)d_in[1];   // [1024,8]
  const float* w1 = (const float*)d_in[2];   // [8,1024,2816]
  const float* w2 = (const float*)d_in[3];   // [8,1408,1024]
  float* out = (float*)d_out;
  char* ws = (char*)d_ws;

  // ws layout (bytes)
  int*   ctrl   = (int*)(ws + 0);                   // 1 KB
  int*   tok_e  = (int*)(ws + 1024);                // 16 KB
  float* tok_p  = (float*)(ws + 17408);             // 16 KB
  int*   stok   = (int*)(ws + 33792);               // 20 KB
  float* sp     = (float*)(ws + 54272);             // 20 KB
  int*   tslot  = (int*)(ws + 74752);               // 16 KB
  int*   widmt1 = (int*)(ws + 91136);               // 3.5 KB
  int*   widmt2 = (int*)(ws + 94656);               // 2.5 KB
  unsigned short* xbf = (unsigned short*)(ws + 97280);        // [T][H]     4 MB
  unsigned short* w1t = (unsigned short*)(ws + 4291584);      // [E][2F][H] 44 MB
  unsigned short* w2t = (unsigned short*)(ws + 50428928);     // [E][H][F]  22 MB
  unsigned short* g   = (unsigned short*)(ws + 73497600);     // [SLOTS][F] 14.5 MB
  // o aliases w1t (w1t dead after k_fc1; rewritten by next replay's k_prep
  // before k_fc1 reads it again).
  float* o = (float*)(ws + 4291584);                          // [SLOTS][H] 21 MB

  hipMemsetAsync(ws, 0, 1024, stream);

  k_prep<<<PREP_NWG, 256, 0, stream>>>(x, rw, w1, w2, w1t, w2t, xbf, ctrl, tok_e, tok_p);
  k_offsets<<<1, 256, 0, stream>>>(ctrl, stok, sp, widmt1, widmt2);
  k_scatter<<<T_TOK / 256, 256, 0, stream>>>(ctrl, tok_e, tok_p, stok, sp, tslot);
  k_fc1<<<FC1_NWG, 256, 0, stream>>>(xbf, w1t, ctrl, stok, sp, widmt1, g);
  k_fc2<<<FC2_NWG, 256, 0, stream>>>(g, w2t, ctrl, widmt2, o);
  k_combine<<<T_TOK, 256, 0, stream>>>(o, tslot, out);
}